// Round 5
// baseline (427.436 us; speedup 1.0000x reference)
//
#include <hip/hip_runtime.h>
#include <cstddef>

#define EMBED   768
#define NHEADS  12
#define HDIM    64
#define KSZ     7
#define IMG_H   64
#define IMG_W   64
#define BATCH   8
#define NTOK    (BATCH*IMG_H*IMG_W)   /* 32768 */
#define QKV_N   (3*EMBED)             /* 2304  */

typedef __attribute__((ext_vector_type(8))) short  bf16x8;
typedef __attribute__((ext_vector_type(4))) float  f32x4;
typedef __attribute__((ext_vector_type(8))) unsigned short u16x8;
typedef __attribute__((ext_vector_type(4))) unsigned short u16x4;

__device__ __forceinline__ unsigned short f2bf(float f) {
    unsigned int u = __float_as_uint(f);
    u += 0x7FFFu + ((u >> 16) & 1u);      // RNE
    return (unsigned short)(u >> 16);
}

__device__ __forceinline__ void gload_lds16(const void* g, void* l) {
    __builtin_amdgcn_global_load_lds(
        (const __attribute__((address_space(1))) unsigned int*)g,
        (__attribute__((address_space(3))) unsigned int*)l, 16, 0, 0);
}

// ---------------- fp32 -> bf16 conversion ----------------
__global__ __launch_bounds__(256)
void cvt_bf16_kernel(const float* __restrict__ in, unsigned short* __restrict__ out, int n4)
{
    int i = blockIdx.x * 256 + threadIdx.x;
    if (i < n4) {
        float4 f = *(const float4*)(in + (size_t)i * 4);
        u16x4 o;
        o[0] = f2bf(f.x); o[1] = f2bf(f.y); o[2] = f2bf(f.z); o[3] = f2bf(f.w);
        *(u16x4*)(out + (size_t)i * 4) = o;
    }
}

// ---------------- bf16 MFMA GEMM v2: fragment-linear LDS, dbuf, 1 barrier/K-step ----
// out[m][n] = A[m][:] . W[n][:] + bias[n]. A: MxK bf16 rm, W: NxK bf16 rm.
// 128x128 tile, BK=32, 256 thr (4 waves), wave -> 64x64, 4x4 frags of 16x16x32.
// LDS layout = MFMA fragment order: subtile s (16 rows x 32 k) occupies 1 KB at
// s*1024; lane l's 16 B slot holds A[row=s*16+(l&15)][k=(l>>4)*8..+7]. Staged by
// global_load_lds whose PER-LANE global address is permuted to fragment order, so
// both write (lane-linear by HW) and read (base + l*16) are conflict-free.
template<int BF16OUT>
__global__ __launch_bounds__(256)
void mfma_gemm(const unsigned short* __restrict__ A, const unsigned short* __restrict__ W,
               const float* __restrict__ bias, void* __restrict__ outp,
               int N, int K, int scaleN, float scale)
{
    __shared__ unsigned short As[2 * 4096];   // 2 bufs x 8 subtiles x 512 ushorts
    __shared__ unsigned short Bs[2 * 4096];
    const int t = threadIdx.x;
    const int l = t & 63, w = t >> 6;
    const int bm = blockIdx.x * 128, bn = blockIdx.y * 128;
    const int wr = (w >> 1) * 64, wc = (w & 1) * 64;

    // staging: wave w stages subtiles {w, w+4} of A and of B.
    // per-lane source in fragment order: row = sub*16 + (l&15), k = (l>>4)*8
    const int r16 = l & 15, kg = l >> 4;
    const unsigned short* gA0 = A + (size_t)(bm + w * 16 + r16) * K + kg * 8;
    const unsigned short* gA1 = A + (size_t)(bm + (w + 4) * 16 + r16) * K + kg * 8;
    const unsigned short* gB0 = W + (size_t)(bn + w * 16 + r16) * K + kg * 8;
    const unsigned short* gB1 = W + (size_t)(bn + (w + 4) * 16 + r16) * K + kg * 8;
    unsigned short* lA0 = As + w * 512;
    unsigned short* lA1 = As + (w + 4) * 512;
    unsigned short* lB0 = Bs + w * 512;
    unsigned short* lB1 = Bs + (w + 4) * 512;

    // fragment read bases: wave w's A-frag i lives in subtile (wr>>4)+i
    const unsigned short* ra = As + ((wr >> 4)) * 512 + l * 8;
    const unsigned short* rb = Bs + ((wc >> 4)) * 512 + l * 8;

    f32x4 acc[4][4] = {};
    const int NT = K / 32;

    // prologue: stage k-step 0 into buf 0
    gload_lds16(gA0, lA0);
    gload_lds16(gA1, lA1);
    gload_lds16(gB0, lB0);
    gload_lds16(gB1, lB1);
    __syncthreads();

    for (int ts = 0; ts < NT; ++ts) {
        const int cur = (ts & 1) * 4096;
        // issue next k-step's staging first (overlaps with ds_read + MFMA below)
        if (ts + 1 < NT) {
            const int nk = (ts + 1) * 32;
            const int nb = ((ts + 1) & 1) * 4096;
            gload_lds16(gA0 + nk, lA0 + nb);
            gload_lds16(gA1 + nk, lA1 + nb);
            gload_lds16(gB0 + nk, lB0 + nb);
            gload_lds16(gB1 + nk, lB1 + nb);
        }
        bf16x8 af[4], bfr[4];
        #pragma unroll
        for (int i = 0; i < 4; ++i) af[i]  = *(const bf16x8*)(ra + cur + i * 512);
        #pragma unroll
        for (int j = 0; j < 4; ++j) bfr[j] = *(const bf16x8*)(rb + cur + j * 512);
        #pragma unroll
        for (int i = 0; i < 4; ++i)
            #pragma unroll
            for (int j = 0; j < 4; ++j)
                acc[i][j] = __builtin_amdgcn_mfma_f32_16x16x32_bf16(af[i], bfr[j], acc[i][j], 0, 0, 0);
        // single barrier per K-step: drains vmcnt (next buf ready) and protects cur
        // buf (fully consumed above) from being overwritten next iteration.
        __syncthreads();
    }

    const int cr = (l >> 4) * 4;
    const int cc = l & 15;
    #pragma unroll
    for (int i = 0; i < 4; ++i) {
        #pragma unroll
        for (int j = 0; j < 4; ++j) {
            const int col = bn + wc + j * 16 + cc;
            const float bv = bias[col];
            const bool sc = col < scaleN;
            #pragma unroll
            for (int r = 0; r < 4; ++r) {
                const int row = bm + wr + i * 16 + cr + r;
                float v = acc[i][j][r] + bv;
                if (sc) v *= scale;
                if (BF16OUT) ((unsigned short*)outp)[(size_t)row * N + col] = f2bf(v);
                else         ((float*)outp)[(size_t)row * N + col] = v;
            }
        }
    }
}

// ---------------- MFMA neighborhood attention (verified round 4) ----------------
__global__ __launch_bounds__(256)
void natten_kernel(const unsigned short* __restrict__ qkv, unsigned short* __restrict__ attn_bf)
{
    __shared__ unsigned short smem[4 * 5888];   // per wave: K 32x72 + V^T 64x56
    const int t = threadIdx.x;
    const int w = t >> 6, l = t & 63;
    const int c15 = l & 15, g = l >> 4;
    const int blk = blockIdx.x;
    const int tg = blk & 15;
    const int h = (blk >> 4) % NHEADS;
    const int b = blk / (16 * NHEADS);
    const int ti = (tg >> 2) * 16, tj = (tg & 3) * 16;
    const int pi0 = ti + w * 4;
    const int ws = min(max(pi0 - 3, 0), IMG_H - 10);
    const int cs = min(max(tj - 3, 0), IMG_W - 22);
    const int pixbase = b * 4096;

    unsigned short* Kl = smem + w * 5888;
    unsigned short* Vt = Kl + 2304;

    const int pj = tj + c15;
    const int sj = min(max(pj - 3, 0), IMG_W - KSZ);
    const unsigned int cm = 0x7Fu << (sj - cs);
    unsigned int rm[4];
    #pragma unroll
    for (int qt = 0; qt < 4; ++qt) {
        int si = min(max(pi0 + qt - 3, 0), IMG_H - KSZ);
        rm[qt] = 0x7Fu << (si - ws);
    }

    bf16x8 qf[4][2];
    #pragma unroll
    for (int qt = 0; qt < 4; ++qt)
        #pragma unroll
        for (int dh = 0; dh < 2; ++dh)
            qf[qt][dh] = *(const bf16x8*)(qkv +
                (size_t)(pixbase + (pi0 + qt) * 64 + tj + c15) * QKV_N + h * HDIM + dh * 32 + g * 8);

    const int sr = l & 31;
    const int h5 = l >> 5;
    const int sig = ((sr & 12) << 1) | ((sr & 16) >> 2) | (sr & 3);  // slot perm 8g+4t+j

    u16x8 kst[4], vst[4];

    {
        int ur = sr / 22, uc = sr - ur * 22;
        int prow = min(ws + ur, IMG_H - 1);
        const u16x8* gk = (const u16x8*)(qkv +
            (size_t)(pixbase + prow * 64 + cs + uc) * QKV_N + EMBED + h * HDIM + h5 * 32);
        #pragma unroll
        for (int i = 0; i < 4; ++i) { kst[i] = gk[i]; vst[i] = gk[i + 96]; }
    }
    #pragma unroll
    for (int i = 0; i < 4; ++i) *(u16x8*)(Kl + sr * 72 + h5 * 32 + i * 8) = kst[i];
    #pragma unroll
    for (int i = 0; i < 4; ++i)
        #pragma unroll
        for (int e = 0; e < 8; ++e)
            Vt[(h5 * 32 + i * 8 + e) * 56 + sig] = vst[i][e];

    f32x4 oacc[4][4] = {};
    float spart[4] = {0.f, 0.f, 0.f, 0.f};

    #pragma unroll 1
    for (int C = 0; C < 7; ++C) {
        if (C < 6) {
            int kk = (C + 1) * 32 + sr;
            int ur = kk / 22, uc = kk - ur * 22;
            int prow = min(ws + ur, IMG_H - 1);
            const u16x8* gk = (const u16x8*)(qkv +
                (size_t)(pixbase + prow * 64 + cs + uc) * QKV_N + EMBED + h * HDIM + h5 * 32);
            #pragma unroll
            for (int i = 0; i < 4; ++i) { kst[i] = gk[i]; vst[i] = gk[i + 96]; }
        }

        bf16x8 ka[2][2], vb[4];
        #pragma unroll
        for (int kt = 0; kt < 2; ++kt)
            #pragma unroll
            for (int dh = 0; dh < 2; ++dh)
                ka[kt][dh] = *(const bf16x8*)(Kl + (kt * 16 + c15) * 72 + dh * 32 + g * 8);
        #pragma unroll
        for (int dt = 0; dt < 4; ++dt)
            vb[dt] = *(const bf16x8*)(Vt + (dt * 16 + c15) * 56 + g * 8);

        int kk0 = C * 32 + 4 * g;
        int a22 = kk0 / 22;
        int uc0 = kk0 - a22 * 22;
        int urx[2][4]; unsigned int cb[2][4];
        #pragma unroll
        for (int kt = 0; kt < 2; ++kt)
            #pragma unroll
            for (int r = 0; r < 4; ++r) {
                int x = uc0 + kt * 16 + r;
                int wrp = x >= 22;
                int uc = x - (wrp ? 22 : 0);
                urx[kt][r] = a22 + wrp;
                cb[kt][r] = (cm >> uc) & 1u;
            }

        #pragma unroll
        for (int qt = 0; qt < 4; ++qt) {
            f32x4 s0 = {}, s1 = {};
            s0 = __builtin_amdgcn_mfma_f32_16x16x32_bf16(ka[0][0], qf[qt][0], s0, 0, 0, 0);
            s0 = __builtin_amdgcn_mfma_f32_16x16x32_bf16(ka[0][1], qf[qt][1], s0, 0, 0, 0);
            s1 = __builtin_amdgcn_mfma_f32_16x16x32_bf16(ka[1][0], qf[qt][0], s1, 0, 0, 0);
            s1 = __builtin_amdgcn_mfma_f32_16x16x32_bf16(ka[1][1], qf[qt][1], s1, 0, 0, 0);
            float p[2][4];
            #pragma unroll
            for (int r = 0; r < 4; ++r) {
                float e0 = exp2f(s0[r]);
                float e1 = exp2f(s1[r]);
                p[0][r] = ((rm[qt] >> urx[0][r]) & cb[0][r]) ? e0 : 0.f;
                p[1][r] = ((rm[qt] >> urx[1][r]) & cb[1][r]) ? e1 : 0.f;
                spart[qt] += p[0][r] + p[1][r];
            }
            unsigned int pk[4];
            asm("v_cvt_pk_bf16_f32 %0, %1, %2" : "=v"(pk[0]) : "v"(p[0][0]), "v"(p[0][1]));
            asm("v_cvt_pk_bf16_f32 %0, %1, %2" : "=v"(pk[1]) : "v"(p[0][2]), "v"(p[0][3]));
            asm("v_cvt_pk_bf16_f32 %0, %1, %2" : "=v"(pk[2]) : "v"(p[1][0]), "v"(p[1][1]));
            asm("v_cvt_pk_bf16_f32 %0, %1, %2" : "=v"(pk[3]) : "v"(p[1][2]), "v"(p[1][3]));
            bf16x8 pa = *(bf16x8*)pk;
            #pragma unroll
            for (int dt = 0; dt < 4; ++dt)
                oacc[qt][dt] = __builtin_amdgcn_mfma_f32_16x16x32_bf16(pa, vb[dt], oacc[qt][dt], 0, 0, 0);
        }

        if (C < 6) {
            #pragma unroll
            for (int i = 0; i < 4; ++i) *(u16x8*)(Kl + sr * 72 + h5 * 32 + i * 8) = kst[i];
            #pragma unroll
            for (int i = 0; i < 4; ++i)
                #pragma unroll
                for (int e = 0; e < 8; ++e)
                    Vt[(h5 * 32 + i * 8 + e) * 56 + sig] = vst[i][e];
        }
    }

    #pragma unroll
    for (int qt = 0; qt < 4; ++qt) {
        float s = spart[qt];
        s += __shfl_xor(s, 16);
        s += __shfl_xor(s, 32);
        #pragma unroll
        for (int r = 0; r < 4; ++r) {
            float sb = __shfl(s, 4 * g + r);
            float inv = __builtin_amdgcn_rcpf(sb);
            size_t obase = (size_t)(pixbase + (pi0 + qt) * 64 + tj + 4 * g + r) * EMBED
                         + h * HDIM + c15;
            #pragma unroll
            for (int dt = 0; dt < 4; ++dt)
                attn_bf[obase + dt * 16] = f2bf(oacc[qt][dt][r] * inv);
        }
    }
}

// ---------------- launch ----------------
extern "C" void kernel_launch(void* const* d_in, const int* in_sizes, int n_in,
                              void* d_out, int out_size, void* d_ws, size_t ws_size,
                              hipStream_t stream)
{
    const float* x      = (const float*)d_in[0];
    const float* w_qkv  = (const float*)d_in[1];
    const float* b_qkv  = (const float*)d_in[2];
    const float* w_proj = (const float*)d_in[3];
    const float* b_proj = (const float*)d_in[4];
    float* out = (float*)d_out;

    // workspace (~206 MB)
    char* p = (char*)d_ws;
    unsigned short* qkv = (unsigned short*)p;     p += (size_t)NTOK * QKV_N * 2;       // 151 MB
    unsigned short* xbf = (unsigned short*)p;     // aliased: x_bf then attn_bf
    unsigned short* attn_bf = xbf;                p += (size_t)NTOK * EMBED * 2;       // 50 MB
    unsigned short* wq_bf = (unsigned short*)p;   p += (size_t)QKV_N * EMBED * 2;      // 3.5 MB
    unsigned short* wp_bf = (unsigned short*)p;

    const float scale = 0.125f * 1.44269504088896f;  // HDIM^-0.5 * log2(e)

    {
        int n4 = NTOK * EMBED / 4;
        cvt_bf16_kernel<<<(n4 + 255) / 256, 256, 0, stream>>>(x, xbf, n4);
        n4 = QKV_N * EMBED / 4;
        cvt_bf16_kernel<<<(n4 + 255) / 256, 256, 0, stream>>>(w_qkv, wq_bf, n4);
        n4 = EMBED * EMBED / 4;
        cvt_bf16_kernel<<<(n4 + 255) / 256, 256, 0, stream>>>(w_proj, wp_bf, n4);
    }

    {
        dim3 g1(NTOK / 128, QKV_N / 128);
        mfma_gemm<1><<<g1, 256, 0, stream>>>(xbf, wq_bf, b_qkv, qkv, QKV_N, EMBED, EMBED, scale);
    }

    natten_kernel<<<BATCH * NHEADS * 16, 256, 0, stream>>>(qkv, attn_bf);

    {
        dim3 g2(NTOK / 128, EMBED / 128);
        mfma_gemm<0><<<g2, 256, 0, stream>>>(attn_bf, wp_bf, b_proj, out, EMBED, EMBED, 0, 1.0f);
    }
}

// Round 6
// 337.497 us; speedup vs baseline: 1.2665x; 1.2665x over previous
//
#include <hip/hip_runtime.h>
#include <cstddef>

#define EMBED   768
#define NHEADS  12
#define HDIM    64
#define KSZ     7
#define IMG_H   64
#define IMG_W   64
#define BATCH   8
#define NTOK    (BATCH*IMG_H*IMG_W)   /* 32768 */
#define QKV_N   (3*EMBED)             /* 2304  */

typedef __attribute__((ext_vector_type(8))) short  bf16x8;
typedef __attribute__((ext_vector_type(4))) float  f32x4;
typedef __attribute__((ext_vector_type(8))) unsigned short u16x8;
typedef __attribute__((ext_vector_type(4))) unsigned short u16x4;

__device__ __forceinline__ unsigned short f2bf(float f) {
    unsigned int u = __float_as_uint(f);
    u += 0x7FFFu + ((u >> 16) & 1u);      // RNE
    return (unsigned short)(u >> 16);
}

__device__ __forceinline__ void gload_lds16(const void* g, void* l) {
    __builtin_amdgcn_global_load_lds(
        (const __attribute__((address_space(1))) unsigned int*)g,
        (__attribute__((address_space(3))) unsigned int*)l, 16, 0, 0);
}

// ---------------- fp32 -> bf16 conversion ----------------
__global__ __launch_bounds__(256)
void cvt_bf16_kernel(const float* __restrict__ in, unsigned short* __restrict__ out, int n4)
{
    int i = blockIdx.x * 256 + threadIdx.x;
    if (i < n4) {
        float4 f = *(const float4*)(in + (size_t)i * 4);
        u16x4 o;
        o[0] = f2bf(f.x); o[1] = f2bf(f.y); o[2] = f2bf(f.z); o[3] = f2bf(f.w);
        *(u16x4*)(out + (size_t)i * 4) = o;
    }
}

// ---------------- bf16 MFMA GEMM v3: 256x256, 8 waves, BK=32, 3-buf counted pipeline ----
// out[m][n] = A[m][:] . W[n][:] + bias[n]. A: MxK bf16 rm, W: NxK bf16 rm.
// Wave (wr2=w>>2, wc4=w&3) owns a 128x64 output: 8 m-frags x 4 n-frags of 16x16x32.
// LDS per buffer: A 16KB (16 subtiles of 16rows x 32k) + B 16KB; 3 buffers = 96KB.
// Subtile layout (both-sides swizzle): (row r, kchunk k) at byte r*64 + ((k^((r>>1)&3))<<4).
//   - gload write is lane-linear (lane l -> byte l*16) => global source: row l>>2 (quad-
//     coalesced 64B), kchunk (l&3)^((l>>3)&3).
//   - ds_read lane l (r=l&15, k=l>>4) spreads 64 lanes evenly over all 8 16B slots -> no
//     bank conflicts.
// Schedule: prefetch 2 tiles ahead; 2 phases/tile {stage 2 glds; ds_read; barrier;
// setprio(1); 16 MFMA; setprio(0); barrier}; s_waitcnt vmcnt(4) once per tile (counted,
// never 0 mid-loop); raw s_barrier (no vmcnt drain).
template<int BF16OUT>
__global__ __launch_bounds__(512)
void gemm256(const unsigned short* __restrict__ A, const unsigned short* __restrict__ W,
             const float* __restrict__ bias, void* __restrict__ outp,
             int M, int N, int K, int scaleN, float scale)
{
    __shared__ unsigned short lds[3 * 16384];   // 96 KiB: buf q at q*16384; B at +8192
    const int t_ = threadIdx.x;
    const int l = t_ & 63, w = t_ >> 6;
    const int wr2 = w >> 2, wc4 = w & 3;

    // XCD-bijective swizzle (nwg % 8 == 0 for both GEMMs here)
    const int nbx = M >> 8;
    const int lin = blockIdx.x;
    const int cpx = gridDim.x >> 3;
    const int swz = (lin & 7) * cpx + (lin >> 3);
    const int bm = (swz % nbx) << 8;
    const int bn = (swz / nbx) << 8;

    // staging source (quad-coalesced, slot-permuted)
    const int kperm = ((l & 3) ^ ((l >> 3) & 3)) * 8;
    const unsigned short* gA = A + (size_t)(bm + w * 16 + (l >> 2)) * K + kperm;
    const unsigned short* gB = W + (size_t)(bn + w * 16 + (l >> 2)) * K + kperm;
    const size_t step8 = (size_t)128 * K;      // subtile index +8

    unsigned short* lA = lds + w * 512;        // + q + i*4096
    unsigned short* lB = lds + 8192 + w * 512;

    // fragment read offset (ushort units): row (l&15), slot (l>>4)^((l>>1)&3)
    const int foff = (l & 15) * 32 + (((l >> 4) ^ ((l >> 1) & 3)) * 8);
    const unsigned short* raw = lds + (wr2 * 8) * 512 + foff;
    const unsigned short* rbw = lds + 8192 + (wc4 * 4) * 512 + foff;

    f32x4 acc[8][4] = {};
    const int NT = K / 32;

    // prologue: stage tiles 0 and 1 (oldest-first), wait tile 0 (vmcnt 4 = tile 1 in flight)
    gload_lds16(gA, lA);              gload_lds16(gA + step8, lA + 4096);
    gload_lds16(gB, lB);              gload_lds16(gB + step8, lB + 4096);
    gload_lds16(gA + 32, lA + 16384); gload_lds16(gA + step8 + 32, lA + 16384 + 4096);
    gload_lds16(gB + 32, lB + 16384); gload_lds16(gB + step8 + 32, lB + 16384 + 4096);
    asm volatile("s_waitcnt vmcnt(4)" ::: "memory");
    __builtin_amdgcn_s_barrier();

    for (int t = 0; t < NT; ++t) {
        const int q  = (t % 3) * 16384;
        const int qn = ((t + 2) % 3) * 16384;
        const bool pf = (t + 2 < NT);
        const int ko = t * 32 + 64;            // k-offset of tile t+2

        // ---- phase 1 (m-frags 0..3) ----
        if (pf) { gload_lds16(gA + ko, lA + qn); gload_lds16(gA + step8 + ko, lA + qn + 4096); }
        bf16x8 af0[4], bf[4];
        #pragma unroll
        for (int m = 0; m < 4; ++m) af0[m] = *(const bf16x8*)(raw + q + m * 512);
        #pragma unroll
        for (int n = 0; n < 4; ++n) bf[n]  = *(const bf16x8*)(rbw + q + n * 512);
        __builtin_amdgcn_s_barrier();
        __builtin_amdgcn_s_setprio(1);
        #pragma unroll
        for (int m = 0; m < 4; ++m)
            #pragma unroll
            for (int n = 0; n < 4; ++n)
                acc[m][n] = __builtin_amdgcn_mfma_f32_16x16x32_bf16(af0[m], bf[n], acc[m][n], 0, 0, 0);
        __builtin_amdgcn_s_setprio(0);
        __builtin_amdgcn_s_barrier();

        // ---- phase 2 (m-frags 4..7) ----
        if (pf) { gload_lds16(gB + ko, lB + qn); gload_lds16(gB + step8 + ko, lB + qn + 4096); }
        bf16x8 af1[4];
        #pragma unroll
        for (int m = 0; m < 4; ++m) af1[m] = *(const bf16x8*)(raw + q + (4 + m) * 512);
        __builtin_amdgcn_s_barrier();
        __builtin_amdgcn_s_setprio(1);
        #pragma unroll
        for (int m = 0; m < 4; ++m)
            #pragma unroll
            for (int n = 0; n < 4; ++n)
                acc[4 + m][n] = __builtin_amdgcn_mfma_f32_16x16x32_bf16(af1[m], bf[n], acc[4 + m][n], 0, 0, 0);
        __builtin_amdgcn_s_setprio(0);
        if (t < NT - 1) {
            // counted wait: tile t+1's 4 loads are the oldest of (up to) 8 outstanding
            if (pf) asm volatile("s_waitcnt vmcnt(4)" ::: "memory");
            else    asm volatile("s_waitcnt vmcnt(0)" ::: "memory");
            __builtin_amdgcn_s_barrier();
        }
    }

    // ---- epilogue ----
    const int cr = (l >> 4) * 4;
    const int cc = l & 15;
    #pragma unroll
    for (int m = 0; m < 8; ++m) {
        #pragma unroll
        for (int n = 0; n < 4; ++n) {
            const int col = bn + wc4 * 64 + n * 16 + cc;
            const float bv = bias[col];
            const bool sc = col < scaleN;
            #pragma unroll
            for (int r = 0; r < 4; ++r) {
                const int row = bm + wr2 * 128 + m * 16 + cr + r;
                float v = acc[m][n][r] + bv;
                if (sc) v *= scale;
                if (BF16OUT) ((unsigned short*)outp)[(size_t)row * N + col] = f2bf(v);
                else         ((float*)outp)[(size_t)row * N + col] = v;
            }
        }
    }
}

// ---------------- MFMA neighborhood attention (verified round 4) ----------------
__global__ __launch_bounds__(256)
void natten_kernel(const unsigned short* __restrict__ qkv, unsigned short* __restrict__ attn_bf)
{
    __shared__ unsigned short smem[4 * 5888];   // per wave: K 32x72 + V^T 64x56
    const int t = threadIdx.x;
    const int w = t >> 6, l = t & 63;
    const int c15 = l & 15, g = l >> 4;
    const int blk = blockIdx.x;
    const int tg = blk & 15;
    const int h = (blk >> 4) % NHEADS;
    const int b = blk / (16 * NHEADS);
    const int ti = (tg >> 2) * 16, tj = (tg & 3) * 16;
    const int pi0 = ti + w * 4;
    const int ws = min(max(pi0 - 3, 0), IMG_H - 10);
    const int cs = min(max(tj - 3, 0), IMG_W - 22);
    const int pixbase = b * 4096;

    unsigned short* Kl = smem + w * 5888;
    unsigned short* Vt = Kl + 2304;

    const int pj = tj + c15;
    const int sj = min(max(pj - 3, 0), IMG_W - KSZ);
    const unsigned int cm = 0x7Fu << (sj - cs);
    unsigned int rm[4];
    #pragma unroll
    for (int qt = 0; qt < 4; ++qt) {
        int si = min(max(pi0 + qt - 3, 0), IMG_H - KSZ);
        rm[qt] = 0x7Fu << (si - ws);
    }

    bf16x8 qf[4][2];
    #pragma unroll
    for (int qt = 0; qt < 4; ++qt)
        #pragma unroll
        for (int dh = 0; dh < 2; ++dh)
            qf[qt][dh] = *(const bf16x8*)(qkv +
                (size_t)(pixbase + (pi0 + qt) * 64 + tj + c15) * QKV_N + h * HDIM + dh * 32 + g * 8);

    const int sr = l & 31;
    const int h5 = l >> 5;
    const int sig = ((sr & 12) << 1) | ((sr & 16) >> 2) | (sr & 3);  // slot perm 8g+4t+j

    u16x8 kst[4], vst[4];

    {
        int ur = sr / 22, uc = sr - ur * 22;
        int prow = min(ws + ur, IMG_H - 1);
        const u16x8* gk = (const u16x8*)(qkv +
            (size_t)(pixbase + prow * 64 + cs + uc) * QKV_N + EMBED + h * HDIM + h5 * 32);
        #pragma unroll
        for (int i = 0; i < 4; ++i) { kst[i] = gk[i]; vst[i] = gk[i + 96]; }
    }
    #pragma unroll
    for (int i = 0; i < 4; ++i) *(u16x8*)(Kl + sr * 72 + h5 * 32 + i * 8) = kst[i];
    #pragma unroll
    for (int i = 0; i < 4; ++i)
        #pragma unroll
        for (int e = 0; e < 8; ++e)
            Vt[(h5 * 32 + i * 8 + e) * 56 + sig] = vst[i][e];

    f32x4 oacc[4][4] = {};
    float spart[4] = {0.f, 0.f, 0.f, 0.f};

    #pragma unroll 1
    for (int C = 0; C < 7; ++C) {
        if (C < 6) {
            int kk = (C + 1) * 32 + sr;
            int ur = kk / 22, uc = kk - ur * 22;
            int prow = min(ws + ur, IMG_H - 1);
            const u16x8* gk = (const u16x8*)(qkv +
                (size_t)(pixbase + prow * 64 + cs + uc) * QKV_N + EMBED + h * HDIM + h5 * 32);
            #pragma unroll
            for (int i = 0; i < 4; ++i) { kst[i] = gk[i]; vst[i] = gk[i + 96]; }
        }

        bf16x8 ka[2][2], vb[4];
        #pragma unroll
        for (int kt = 0; kt < 2; ++kt)
            #pragma unroll
            for (int dh = 0; dh < 2; ++dh)
                ka[kt][dh] = *(const bf16x8*)(Kl + (kt * 16 + c15) * 72 + dh * 32 + g * 8);
        #pragma unroll
        for (int dt = 0; dt < 4; ++dt)
            vb[dt] = *(const bf16x8*)(Vt + (dt * 16 + c15) * 56 + g * 8);

        int kk0 = C * 32 + 4 * g;
        int a22 = kk0 / 22;
        int uc0 = kk0 - a22 * 22;
        int urx[2][4]; unsigned int cb[2][4];
        #pragma unroll
        for (int kt = 0; kt < 2; ++kt)
            #pragma unroll
            for (int r = 0; r < 4; ++r) {
                int x = uc0 + kt * 16 + r;
                int wrp = x >= 22;
                int uc = x - (wrp ? 22 : 0);
                urx[kt][r] = a22 + wrp;
                cb[kt][r] = (cm >> uc) & 1u;
            }

        #pragma unroll
        for (int qt = 0; qt < 4; ++qt) {
            f32x4 s0 = {}, s1 = {};
            s0 = __builtin_amdgcn_mfma_f32_16x16x32_bf16(ka[0][0], qf[qt][0], s0, 0, 0, 0);
            s0 = __builtin_amdgcn_mfma_f32_16x16x32_bf16(ka[0][1], qf[qt][1], s0, 0, 0, 0);
            s1 = __builtin_amdgcn_mfma_f32_16x16x32_bf16(ka[1][0], qf[qt][0], s1, 0, 0, 0);
            s1 = __builtin_amdgcn_mfma_f32_16x16x32_bf16(ka[1][1], qf[qt][1], s1, 0, 0, 0);
            float p[2][4];
            #pragma unroll
            for (int r = 0; r < 4; ++r) {
                float e0 = exp2f(s0[r]);
                float e1 = exp2f(s1[r]);
                p[0][r] = ((rm[qt] >> urx[0][r]) & cb[0][r]) ? e0 : 0.f;
                p[1][r] = ((rm[qt] >> urx[1][r]) & cb[1][r]) ? e1 : 0.f;
                spart[qt] += p[0][r] + p[1][r];
            }
            unsigned int pk[4];
            asm("v_cvt_pk_bf16_f32 %0, %1, %2" : "=v"(pk[0]) : "v"(p[0][0]), "v"(p[0][1]));
            asm("v_cvt_pk_bf16_f32 %0, %1, %2" : "=v"(pk[1]) : "v"(p[0][2]), "v"(p[0][3]));
            asm("v_cvt_pk_bf16_f32 %0, %1, %2" : "=v"(pk[2]) : "v"(p[1][0]), "v"(p[1][1]));
            asm("v_cvt_pk_bf16_f32 %0, %1, %2" : "=v"(pk[3]) : "v"(p[1][2]), "v"(p[1][3]));
            bf16x8 pa = *(bf16x8*)pk;
            #pragma unroll
            for (int dt = 0; dt < 4; ++dt)
                oacc[qt][dt] = __builtin_amdgcn_mfma_f32_16x16x32_bf16(pa, vb[dt], oacc[qt][dt], 0, 0, 0);
        }

        if (C < 6) {
            #pragma unroll
            for (int i = 0; i < 4; ++i) *(u16x8*)(Kl + sr * 72 + h5 * 32 + i * 8) = kst[i];
            #pragma unroll
            for (int i = 0; i < 4; ++i)
                #pragma unroll
                for (int e = 0; e < 8; ++e)
                    Vt[(h5 * 32 + i * 8 + e) * 56 + sig] = vst[i][e];
        }
    }

    #pragma unroll
    for (int qt = 0; qt < 4; ++qt) {
        float s = spart[qt];
        s += __shfl_xor(s, 16);
        s += __shfl_xor(s, 32);
        #pragma unroll
        for (int r = 0; r < 4; ++r) {
            float sb = __shfl(s, 4 * g + r);
            float inv = __builtin_amdgcn_rcpf(sb);
            size_t obase = (size_t)(pixbase + (pi0 + qt) * 64 + tj + 4 * g + r) * EMBED
                         + h * HDIM + c15;
            #pragma unroll
            for (int dt = 0; dt < 4; ++dt)
                attn_bf[obase + dt * 16] = f2bf(oacc[qt][dt][r] * inv);
        }
    }
}

// ---------------- launch ----------------
extern "C" void kernel_launch(void* const* d_in, const int* in_sizes, int n_in,
                              void* d_out, int out_size, void* d_ws, size_t ws_size,
                              hipStream_t stream)
{
    const float* x      = (const float*)d_in[0];
    const float* w_qkv  = (const float*)d_in[1];
    const float* b_qkv  = (const float*)d_in[2];
    const float* w_proj = (const float*)d_in[3];
    const float* b_proj = (const float*)d_in[4];
    float* out = (float*)d_out;

    // workspace (~206 MB)
    char* p = (char*)d_ws;
    unsigned short* qkv = (unsigned short*)p;     p += (size_t)NTOK * QKV_N * 2;       // 151 MB
    unsigned short* xbf = (unsigned short*)p;     // aliased: x_bf then attn_bf
    unsigned short* attn_bf = xbf;                p += (size_t)NTOK * EMBED * 2;       // 50 MB
    unsigned short* wq_bf = (unsigned short*)p;   p += (size_t)QKV_N * EMBED * 2;      // 3.5 MB
    unsigned short* wp_bf = (unsigned short*)p;

    const float scale = 0.125f * 1.44269504088896f;  // HDIM^-0.5 * log2(e)

    {
        int n4 = NTOK * EMBED / 4;
        cvt_bf16_kernel<<<(n4 + 255) / 256, 256, 0, stream>>>(x, xbf, n4);
        n4 = QKV_N * EMBED / 4;
        cvt_bf16_kernel<<<(n4 + 255) / 256, 256, 0, stream>>>(w_qkv, wq_bf, n4);
        n4 = EMBED * EMBED / 4;
        cvt_bf16_kernel<<<(n4 + 255) / 256, 256, 0, stream>>>(w_proj, wp_bf, n4);
    }

    {
        // GEMM1: M=32768, N=2304 -> 128 x 9 = 1152 blocks (nwg % 8 == 0)
        gemm256<1><<<(NTOK / 256) * (QKV_N / 256), 512, 0, stream>>>(
            xbf, wq_bf, b_qkv, qkv, NTOK, QKV_N, EMBED, EMBED, scale);
    }

    natten_kernel<<<BATCH * NHEADS * 16, 256, 0, stream>>>(qkv, attn_bf);

    {
        // GEMM2: M=32768, N=768 -> 128 x 3 = 384 blocks (nwg % 8 == 0)
        gemm256<0><<<(NTOK / 256) * (EMBED / 256), 512, 0, stream>>>(
            attn_bf, wp_bf, b_proj, out, NTOK, EMBED, EMBED, 0, 1.0f);
    }
}